// Round 14
// baseline (925.563 us; speedup 1.0000x reference)
//
#include <hip/hip_runtime.h>

typedef short short8 __attribute__((ext_vector_type(8)));
typedef float f32x4 __attribute__((ext_vector_type(4)));

#define XP_BYTES (16ull * 130 * 130 * 128 * 2)

static __device__ __forceinline__ unsigned short f2bf(float f) {
  unsigned u = __float_as_uint(f);
  u += 0x7FFFu + ((u >> 16) & 1u);
  return (unsigned short)(u >> 16);
}

static __device__ __forceinline__ void gload16(const void* g, void* l) {
  __builtin_amdgcn_global_load_lds(
      (const __attribute__((address_space(1))) void*)g,
      (__attribute__((address_space(3))) void*)l, 16, 0, 0);
}

// ---------------- weight rotation: (O*R,I,3,3) fp32 -> W2[n'=o*8+r][tap*128+ic] bf16
static __device__ __forceinline__ float wtap(const float* f, int yi, int xi) {
  bool valid = (yi >= 0) & (yi < 3) & (xi >= 0) & (xi < 3);
  int yc = min(max(yi, 0), 2), xc = min(max(xi, 0), 2);
  return valid ? f[yc * 3 + xc] : 0.f;
}

__global__ __launch_bounds__(256) void wprep_kernel(
    const float* __restrict__ w, const float* __restrict__ rot_alpha,
    unsigned short* __restrict__ w2) {
  int gid = blockIdx.x * 256 + threadIdx.x;  // 131072 = 1024 * 128
  int ic = gid & 127;
  int nr = gid >> 7;  // n' = o*8 + r
  int r = nr & 7;
  const float* wf = w + (size_t)nr * (128 * 9) + (size_t)ic * 9;
  float f[9];
#pragma unroll
  for (int q = 0; q < 9; ++q) f[q] = wf[q];
  float ang = rot_alpha[r] * 0.78539816339744830962f * (float)r;
  float sth, cth;
  sincosf(ang, &sth, &cth);
#pragma unroll
  for (int j = 0; j < 3; ++j) {
#pragma unroll
    for (int i = 0; i < 3; ++i) {
      float gy = (float)(j - 1), gx = (float)(i - 1);
      float xs = cth * gx - sth * gy;
      float ys = sth * gx + cth * gy;
      float ix = xs + 1.0f, iy = ys + 1.0f;
      float x0f = floorf(ix), y0f = floorf(iy);
      int x0 = (int)x0f, y0 = (int)y0f;
      float wx = ix - x0f, wy = iy - y0f;
      float acc = wtap(f, y0, x0) * (1.f - wy) * (1.f - wx)
                + wtap(f, y0, x0 + 1) * (1.f - wy) * wx
                + wtap(f, y0 + 1, x0) * wy * (1.f - wx)
                + wtap(f, y0 + 1, x0 + 1) * wy * wx;
      w2[(size_t)nr * 1152 + (size_t)(j * 3 + i) * 128 + ic] = f2bf(acc);
    }
  }
}

// ---------------- x: NCHW fp32 -> padded NHWC bf16 xp[16][130][130][128]
__global__ __launch_bounds__(256) void xprep_kernel(
    const float* __restrict__ x, unsigned short* __restrict__ xp) {
  const int yy = blockIdx.x;  // 0..129
  const int b = blockIdx.y;   // 0..15
  const int t = threadIdx.x;
  const size_t rowbase = ((size_t)b * 130 + yy) * (130 * 128);
  if (yy == 0 || yy == 129) {
    uint4 z = {0u, 0u, 0u, 0u};
    for (int i = t; i < 2080; i += 256)
      ((uint4*)(xp + rowbase))[i] = z;
    return;
  }
  const int y = yy - 1;
  __shared__ float lt[32][129];
  if (t < 32) {
    uint4 z = {0u, 0u, 0u, 0u};
    int xx = (t < 16) ? 0 : 129;
    int cc = (t & 15) * 8;
    *(uint4*)(xp + rowbase + (size_t)xx * 128 + cc) = z;
  }
  for (int c0 = 0; c0 < 128; c0 += 32) {
#pragma unroll
    for (int i = 0; i < 16; ++i) {
      int idx = i * 256 + t;
      int c = idx >> 7, wq = idx & 127;
      lt[c][wq] = x[(((size_t)b * 128 + c0 + c) * 128 + y) * 128 + wq];
    }
    __syncthreads();
#pragma unroll
    for (int i = 0; i < 2; ++i) {
      int u = i * 256 + t;
      int xx = u >> 2, cp = (u & 3) * 8;
      unsigned short v[8];
#pragma unroll
      for (int q = 0; q < 8; ++q) v[q] = f2bf(lt[cp + q][xx]);
      *(uint4*)(xp + rowbase + (size_t)(xx + 1) * 128 + c0 + cp) = *(uint4*)v;
    }
    __syncthreads();
  }
}

// ---------------- implicit-GEMM conv, 128x128 tile, BK=32, 4 waves, 4 blocks/CU.
// A staged as 130-PIXEL STRIPS once per (chq,dy) — the 3 dx-taps read the same
// strip at +dx row offset (A write traffic -66%). B double-buffered per K-step.
// K-step st = 3*(chq*3+dy) + dx, 36 total. Depth-1 staging, vmcnt(0) (R11 sched).
// LDS: A[2][132 rows][32k] @0 (4224 shorts/buf) + B[2][128 n'][32k] @8448.
__global__ __launch_bounds__(256, 4) void conv_kernel(
    const unsigned short* __restrict__ xp,
    const unsigned short* __restrict__ w2,
    float* __restrict__ out) {
  __shared__ unsigned short lds[16640];  // 33280 B

  const int tid = threadIdx.x;
  const int lane = tid & 63;
  const int wv = tid >> 6;  // 0..3
  const int wr = wv >> 1;   // M half (64 rows)
  const int wc = wv & 1;    // N half (64 n')

  const int bid = blockIdx.x;
  const int wg = (bid & 7) * 2048 + (bid >> 3);  // XCD swizzle (16384 % 8 == 0)
  const int mblk = wg >> 3;  // 0..2047
  const int nblk = wg & 7;   // 0..7
  const int b = mblk >> 7;
  const int y = mblk & 127;

  // staging decode: thread t covers row r0 (0..63), lds slot s0 (16B, 4/row)
  const int r0 = tid >> 2;
  const int s0 = tid & 3;
  const int g0 = s0 ^ ((r0 >> 1) & 3);  // inverse swizzle on global source

  const unsigned short* xpt =
      xp + (size_t)(b * 130 + y) * 130 * 128 + r0 * 128 + g0 * 8;
  const unsigned short* wpt =
      w2 + (size_t)nblk * 128 * 1152 + (size_t)r0 * 1152 + g0 * 8;

  const int l15 = lane & 15;
  const int lhi = lane >> 4;
  // dx-shifted read addressing (strip row = l15 + q*16 + wr*64 + dx)
  const int aRd0 = wr * 2048 + (l15 + 0) * 32 + ((lhi ^ (((l15 + 0) >> 1) & 3)) * 8);
  const int aRd1 = wr * 2048 + (l15 + 1) * 32 + ((lhi ^ (((l15 + 1) >> 1) & 3)) * 8);
  const int aRd2 = wr * 2048 + (l15 + 2) * 32 + ((lhi ^ (((l15 + 2) >> 1) & 3)) * 8);
  const int bRd = wc * 2048 + l15 * 32 + ((lhi ^ ((l15 >> 1) & 3)) * 8);

  f32x4 acc[4][4];
#pragma unroll
  for (int mf = 0; mf < 4; ++mf)
#pragma unroll
    for (int nf = 0; nf < 4; ++nf) acc[mf][nf] = (f32x4){0.f, 0.f, 0.f, 0.f};

  // stage A strip S (dy=S%3, chq=S/3): 130 pixels x 32 ch into buf BUFA
#define STAGE_A_STRIP(BUFA, S)                                                \
  {                                                                           \
    const int dy_ = (S) % 3, cq_ = (S) / 3;                                   \
    const unsigned short* src_ = xpt + (size_t)dy_ * 130 * 128 + cq_ * 32;    \
    gload16(src_, lds + (BUFA) * 4224 + wv * 512);                            \
    gload16(src_ + 64 * 128, lds + (BUFA) * 4224 + 2048 + wv * 512);          \
    if (tid < 8) {                                                            \
      const unsigned short* ts_ =                                             \
          xp + ((size_t)(b * 130 + y + dy_)) * 130 * 128 +                    \
          (size_t)(128 + (tid >> 2)) * 128 + cq_ * 32 + (tid & 3) * 8;        \
      gload16(ts_, lds + (BUFA) * 4224 + 4096);                               \
    }                                                                         \
  }

  // stage B tile (tap, chq) into buf BUFB
#define STAGE_B_T(BUFB, TAP, CQ)                                              \
  {                                                                           \
    gload16(wpt + (TAP) * 128 + (CQ) * 32,                                    \
            lds + 8448 + (BUFB) * 4096 + wv * 512);                           \
    gload16(wpt + (size_t)64 * 1152 + (TAP) * 128 + (CQ) * 32,                \
            lds + 8448 + (BUFB) * 4096 + 2048 + wv * 512);                    \
  }

#define VMW0 asm volatile("s_waitcnt vmcnt(0)" ::: "memory")
#define SCH0 __builtin_amdgcn_sched_barrier(0)

#define BODY(BUFA, BUFB, ARD, STG)                                            \
  {                                                                           \
    STG;                                                                      \
    const unsigned short* pA_ = lds + (BUFA) * 4224 + (ARD);                  \
    const unsigned short* pB_ = lds + 8448 + (BUFB) * 4096 + bRd;             \
    short8 af[4], bf[4];                                                      \
    _Pragma("unroll") for (int q = 0; q < 4; ++q)                             \
        af[q] = *(const short8*)(pA_ + q * 512);                              \
    _Pragma("unroll") for (int n = 0; n < 4; ++n)                             \
        bf[n] = *(const short8*)(pB_ + n * 512);                              \
    __builtin_amdgcn_s_setprio(1);                                            \
    _Pragma("unroll") for (int q = 0; q < 4; ++q)                             \
        _Pragma("unroll") for (int n = 0; n < 4; ++n)                         \
            acc[q][n] = __builtin_amdgcn_mfma_f32_16x16x32_bf16(              \
                af[q], bf[n], acc[q][n], 0, 0, 0);                            \
    __builtin_amdgcn_s_setprio(0);                                            \
    SCH0;                                                                     \
    VMW0;                                                                     \
    __builtin_amdgcn_s_barrier();                                             \
  }

  // ---- prologue: stage strip 0 -> bufA0, B(tap of s0, dx=0) -> bufB0
  STAGE_A_STRIP(0, 0);
  STAGE_B_T(0, 0, 0);
  VMW0;
  SCH0;
  __builtin_amdgcn_s_barrier();

#pragma unroll 1
  for (int j = 0; j < 6; ++j) {
    {  // s even: bufA 0; bufB over dx = 0,1,0
      const int s_ = 2 * j;
      const int dy_ = s_ % 3, cq_ = s_ / 3;
      const int tap_ = dy_ * 3;
      const int dyn_ = (s_ + 1) % 3, cqn_ = (s_ + 1) / 3;
      BODY(0, 0, aRd0, STAGE_B_T(1, tap_ + 1, cq_));
      BODY(0, 1, aRd1, { STAGE_A_STRIP(1, s_ + 1); STAGE_B_T(0, tap_ + 2, cq_); });
      BODY(0, 0, aRd2, STAGE_B_T(1, dyn_ * 3, cqn_));
    }
    {  // s odd: bufA 1; bufB over dx = 1,0,1
      const int s_ = 2 * j + 1;
      const int dy_ = s_ % 3, cq_ = s_ / 3;
      const int tap_ = dy_ * 3;
      const bool more_ = s_ < 11;
      const int dyn_ = (s_ + 1) % 3, cqn_ = (s_ + 1) / 3;
      BODY(1, 1, aRd0, STAGE_B_T(0, tap_ + 1, cq_));
      BODY(1, 0, aRd1, { if (more_) STAGE_A_STRIP(0, s_ + 1); STAGE_B_T(1, tap_ + 2, cq_); });
      BODY(1, 1, aRd2, { if (more_) STAGE_B_T(0, dyn_ * 3, cqn_); });
    }
  }

#undef BODY
#undef STAGE_A_STRIP
#undef STAGE_B_T
#undef VMW0
#undef SCH0

  // ---- epilogue: max over 8 rotations (8 adjacent n' cols), coalesced store
  float* lE = (float*)lds;  // [128 pix][17] fp32
#pragma unroll
  for (int mf = 0; mf < 4; ++mf)
#pragma unroll
    for (int nf = 0; nf < 4; ++nf)
#pragma unroll
      for (int j = 0; j < 4; ++j) {
        float v = acc[mf][nf][j];
        v = fmaxf(v, __shfl_xor(v, 1, 64));
        v = fmaxf(v, __shfl_xor(v, 2, 64));
        v = fmaxf(v, __shfl_xor(v, 4, 64));
        if ((lane & 7) == 0) {
          int pix = wr * 64 + mf * 16 + lhi * 4 + j;
          int ol = wc * 8 + nf * 2 + ((lane >> 3) & 1);
          lE[pix * 17 + ol] = v;
        }
      }
  __syncthreads();
  const size_t obase = ((size_t)(b * 128 + nblk * 16) * 128 + y) * 128;
#pragma unroll
  for (int i = 0; i < 8; ++i) {
    int idx = i * 256 + tid;
    int ol = idx >> 7;   // 0..15
    int xx = idx & 127;
    out[obase + (size_t)ol * 16384 + xx] = lE[xx * 17 + ol];
  }
}

extern "C" void kernel_launch(void* const* d_in, const int* in_sizes, int n_in,
                              void* d_out, int out_size, void* d_ws, size_t ws_size,
                              hipStream_t stream) {
  const float* x = (const float*)d_in[0];
  const float* w = (const float*)d_in[1];
  const float* ra = (const float*)d_in[2];
  float* out = (float*)d_out;
  unsigned short* xp = (unsigned short*)d_ws;
  unsigned short* w2 = (unsigned short*)((char*)d_ws + XP_BYTES);

  hipLaunchKernelGGL(wprep_kernel, dim3(512), dim3(256), 0, stream, w, ra, w2);
  hipLaunchKernelGGL(xprep_kernel, dim3(130, 16), dim3(256), 0, stream, x, xp);
  hipLaunchKernelGGL(conv_kernel, dim3(16384), dim3(256), 0, stream, xp, w2, out);
}